// Round 1
// baseline (226.201 us; speedup 1.0000x reference)
//
#include <hip/hip_runtime.h>
#include <stdint.h>

typedef unsigned short u16;
typedef __attribute__((ext_vector_type(8))) __bf16 bf16x8;
typedef __attribute__((ext_vector_type(4))) float f32x4;

#define BM 128
#define BN 128
#define BK 32

__device__ __forceinline__ u16 f2bf(float f) {
  union { float f; uint32_t u; } c; c.f = f;
  uint32_t u = c.u + 0x7fffu + ((c.u >> 16) & 1u);
  return (u16)(u >> 16);
}

__device__ __forceinline__ void async16(const u16* g, u16* l) {
  __builtin_amdgcn_global_load_lds(
      (const __attribute__((address_space(1))) void*)g,
      (__attribute__((address_space(3))) void*)l, 16, 0, 0);
}

__device__ __forceinline__ f32x4 mfma16(bf16x8 a, bf16x8 b, f32x4 c) {
  return __builtin_amdgcn_mfma_f32_16x16x32_bf16(a, b, c, 0, 0, 0);
}

// ---------------- conversion kernels ----------------

__global__ __launch_bounds__(256) void x_cvt_kernel(const float* __restrict__ x,
                                                    u16* __restrict__ xb) {
  int i = (blockIdx.x * 256 + threadIdx.x) * 4;
  float4 v = *(const float4*)(x + i);
  uint32_t p0 = (uint32_t)f2bf(v.x) | ((uint32_t)f2bf(v.y) << 16);
  uint32_t p1 = (uint32_t)f2bf(v.z) | ((uint32_t)f2bf(v.w) << 16);
  uint2 t; t.x = p0; t.y = p1;
  *(uint2*)(xb + i) = t;
}

// W [K=1024][N=1024] fp32  ->  WT [N][K] bf16
__global__ __launch_bounds__(256) void wt_cvt_kernel(const float* __restrict__ Wq,
                                                     const float* __restrict__ Wk,
                                                     const float* __restrict__ Wv,
                                                     const float* __restrict__ Wo,
                                                     u16* __restrict__ out) {
  __shared__ __align__(16) u16 t[64][72];
  int z = blockIdx.z;
  const float* W = (z == 0) ? Wq : (z == 1) ? Wk : (z == 2) ? Wv : Wo;
  u16* o = out + (size_t)z * (1u << 20);
  int n0 = blockIdx.x * 64, k0 = blockIdx.y * 64;
  int tid = threadIdx.x;
  int c4 = (tid & 15) * 4, r0 = tid >> 4;
#pragma unroll
  for (int i = 0; i < 4; i++) {
    int r = r0 + i * 16;
    float4 v = *(const float4*)(W + (size_t)(k0 + r) * 1024 + n0 + c4);
    t[c4 + 0][r] = f2bf(v.x);
    t[c4 + 1][r] = f2bf(v.y);
    t[c4 + 2][r] = f2bf(v.z);
    t[c4 + 3][r] = f2bf(v.w);
  }
  __syncthreads();
  int n = tid >> 2, kc = (tid & 3) * 16;
  uint4 a = *(const uint4*)&t[n][kc];
  uint4 b = *(const uint4*)&t[n][kc + 8];
  *(uint4*)(o + (size_t)(n0 + n) * 1024 + k0 + kc) = a;
  *(uint4*)(o + (size_t)(n0 + n) * 1024 + k0 + kc + 8) = b;
}

// ---------------- GEMM core (A [M][1024] bf16, Bt [N][1024] bf16) ----------------

__device__ __forceinline__ void gemm_core(const u16* __restrict__ A,
                                          const u16* __restrict__ Bt,
                                          u16* As, u16* Bs, f32x4 (&acc)[4][4]) {
  const int tid = threadIdx.x, wave = tid >> 6, lane = tid & 63;
  const int low = lane & 15, hi = lane >> 4;
  const int wm = wave >> 1, wn = wave & 1;
  const int m0 = blockIdx.y * BM, n0 = blockIdx.x * BN;
  const f32x4 fzero = {0.f, 0.f, 0.f, 0.f};
#pragma unroll
  for (int i = 0; i < 4; i++)
#pragma unroll
    for (int j = 0; j < 4; j++) acc[i][j] = fzero;

  const u16* ap = As + (wm * 64 + low) * BK + hi * 8;
  const u16* bp = Bs + (wn * 64 + low) * BK + hi * 8;

  const int e0 = wave * 128 + lane;
  const int e1 = e0 + 64;
  const u16* ga0 = A + (size_t)(m0 + (e0 >> 2)) * 1024 + (e0 & 3) * 8;
  const u16* ga1 = A + (size_t)(m0 + (e1 >> 2)) * 1024 + (e1 & 3) * 8;
  const u16* gb0 = Bt + (size_t)(n0 + (e0 >> 2)) * 1024 + (e0 & 3) * 8;
  const u16* gb1 = Bt + (size_t)(n0 + (e1 >> 2)) * 1024 + (e1 & 3) * 8;
  u16* la0 = As + (wave * 2 + 0) * 512;
  u16* la1 = As + (wave * 2 + 1) * 512;
  u16* lb0 = Bs + (wave * 2 + 0) * 512;
  u16* lb1 = Bs + (wave * 2 + 1) * 512;

  for (int kt = 0; kt < 1024; kt += BK) {
    __syncthreads();
    async16(ga0 + kt, la0);
    async16(ga1 + kt, la1);
    async16(gb0 + kt, lb0);
    async16(gb1 + kt, lb1);
    __syncthreads();
    bf16x8 af[4], bfv[4];
#pragma unroll
    for (int i = 0; i < 4; i++) af[i] = *(const bf16x8*)(ap + i * 16 * BK);
#pragma unroll
    for (int j = 0; j < 4; j++) bfv[j] = *(const bf16x8*)(bp + j * 16 * BK);
#pragma unroll
    for (int i = 0; i < 4; i++)
#pragma unroll
      for (int j = 0; j < 4; j++) acc[i][j] = mfma16(af[i], bfv[j], acc[i][j]);
  }
}

// QKV projection: out layouts  Q,K -> [BH][L][64],  V -> [BH][64][L]
__global__ __launch_bounds__(256) void gemm_qkv_kernel(
    const u16* __restrict__ xb, const u16* __restrict__ wT,
    const float* __restrict__ bq, const float* __restrict__ bk,
    const float* __restrict__ bv,
    u16* __restrict__ qs, u16* __restrict__ ks, u16* __restrict__ vts) {
  __shared__ __align__(16) u16 As[BM * BK];
  __shared__ __align__(16) u16 Bs[BN * BK];
  const int z = blockIdx.z;
  const u16* Bt = wT + (size_t)z * (1u << 20);
  f32x4 acc[4][4];
  gemm_core(xb, Bt, As, Bs, acc);

  const float* bias = (z == 0) ? bq : (z == 1) ? bk : bv;
  u16* out = (z == 0) ? qs : (z == 1) ? ks : vts;
  const int tid = threadIdx.x, wave = tid >> 6, lane = tid & 63;
  const int low = lane & 15, hi = lane >> 4;
  const int wm = wave >> 1, wn = wave & 1;
  const int m0 = blockIdx.y * BM, n0 = blockIdx.x * BN;
#pragma unroll
  for (int i = 0; i < 4; i++)
#pragma unroll
    for (int j = 0; j < 4; j++) {
      int gn = n0 + wn * 64 + j * 16 + low;
      float bval = bias[gn];
      int h = gn >> 6, hd = gn & 63;
#pragma unroll
      for (int r = 0; r < 4; r++) {
        int gm = m0 + wm * 64 + i * 16 + hi * 4 + r;
        int b = gm >> 11, l = gm & 2047;
        float v = acc[i][j][r] + bval;
        size_t addr;
        if (z == 2) addr = ((size_t)((b * 16 + h) * 64 + hd)) * 2048 + l;
        else        addr = ((size_t)((b * 16 + h) * 2048 + l)) * 64 + hd;
        out[addr] = f2bf(v);
      }
    }
}

// output projection: ctx[M][1024] @ WoT + bo -> fp32 out[M][1024]
__global__ __launch_bounds__(256) void gemm_out_kernel(
    const u16* __restrict__ ctx, const u16* __restrict__ woT,
    const float* __restrict__ bo, float* __restrict__ out) {
  __shared__ __align__(16) u16 As[BM * BK];
  __shared__ __align__(16) u16 Bs[BN * BK];
  f32x4 acc[4][4];
  gemm_core(ctx, woT, As, Bs, acc);
  const int tid = threadIdx.x, wave = tid >> 6, lane = tid & 63;
  const int low = lane & 15, hi = lane >> 4;
  const int wm = wave >> 1, wn = wave & 1;
  const int m0 = blockIdx.y * BM, n0 = blockIdx.x * BN;
#pragma unroll
  for (int i = 0; i < 4; i++)
#pragma unroll
    for (int j = 0; j < 4; j++) {
      int gn = n0 + wn * 64 + j * 16 + low;
      float bval = bo[gn];
#pragma unroll
      for (int r = 0; r < 4; r++) {
        int gm = m0 + wm * 64 + i * 16 + hi * 4 + r;
        out[(size_t)gm * 1024 + gn] = acc[i][j][r] + bval;
      }
    }
}

// ---------------- flash attention ----------------
// grid (L/64, BH). 4 waves x 16 q-rows. K tile [64 k][64 d], V tile [64 hd][64 k].
__global__ __launch_bounds__(256) void flash_kernel(
    const u16* __restrict__ Qs, const u16* __restrict__ Ks,
    const u16* __restrict__ Vts, u16* __restrict__ ctx) {
  __shared__ __align__(16) u16 Kls[64 * 64];
  __shared__ __align__(16) u16 Vls[64 * 64];
  __shared__ __align__(16) u16 Pls[4][16 * 64];
  const int bh = blockIdx.y, qb = blockIdx.x * 64;
  const int tid = threadIdx.x, wave = tid >> 6, lane = tid & 63;
  const int low = lane & 15, hi = lane >> 4;
  const u16* Qb = Qs + (size_t)bh * (2048 * 64);
  const u16* Kb = Ks + (size_t)bh * (2048 * 64);
  const u16* Vb = Vts + (size_t)bh * (64 * 2048);
  const f32x4 fzero = {0.f, 0.f, 0.f, 0.f};

  const int qr = qb + wave * 16 + low;
  bf16x8 qf0 = *(const bf16x8*)(Qb + (size_t)qr * 64 + hi * 8);
  bf16x8 qf1 = *(const bf16x8*)(Qb + (size_t)qr * 64 + 32 + hi * 8);

  f32x4 o[4];
  float mrow[4], lrow[4];
#pragma unroll
  for (int nt = 0; nt < 4; nt++) o[nt] = fzero;
#pragma unroll
  for (int r = 0; r < 4; r++) { mrow[r] = -1e30f; lrow[r] = 0.f; }

  const int e0 = wave * 128 + lane, e1 = e0 + 64;

  for (int kt0 = 0; kt0 <= qb; kt0 += 64) {
    __syncthreads();
    async16(Kb + (size_t)(kt0 + (e0 >> 3)) * 64 + (e0 & 7) * 8, Kls + (wave * 2 + 0) * 512);
    async16(Kb + (size_t)(kt0 + (e1 >> 3)) * 64 + (e1 & 7) * 8, Kls + (wave * 2 + 1) * 512);
    async16(Vb + (size_t)(e0 >> 3) * 2048 + kt0 + (e0 & 7) * 8, Vls + (wave * 2 + 0) * 512);
    async16(Vb + (size_t)(e1 >> 3) * 2048 + kt0 + (e1 & 7) * 8, Vls + (wave * 2 + 1) * 512);
    __syncthreads();

    f32x4 s[4];
#pragma unroll
    for (int nt = 0; nt < 4; nt++) {
      s[nt] = fzero;
      bf16x8 kf0 = *(const bf16x8*)(Kls + (nt * 16 + low) * 64 + hi * 8);
      bf16x8 kf1 = *(const bf16x8*)(Kls + (nt * 16 + low) * 64 + 32 + hi * 8);
      s[nt] = mfma16(qf0, kf0, s[nt]);
      s[nt] = mfma16(qf1, kf1, s[nt]);
    }

    float pm[4];
#pragma unroll
    for (int r = 0; r < 4; r++) pm[r] = -1e30f;
#pragma unroll
    for (int nt = 0; nt < 4; nt++)
#pragma unroll
      for (int r = 0; r < 4; r++) {
        float v = s[nt][r] * 0.125f;
        int kg = kt0 + nt * 16 + low;
        int qg = qb + wave * 16 + hi * 4 + r;
        if (kg > qg) v = -1e30f;
        s[nt][r] = v;
        pm[r] = fmaxf(pm[r], v);
      }
#pragma unroll
    for (int r = 0; r < 4; r++) {
      pm[r] = fmaxf(pm[r], __shfl_xor(pm[r], 1));
      pm[r] = fmaxf(pm[r], __shfl_xor(pm[r], 2));
      pm[r] = fmaxf(pm[r], __shfl_xor(pm[r], 4));
      pm[r] = fmaxf(pm[r], __shfl_xor(pm[r], 8));
    }
    float corr[4], rs[4];
#pragma unroll
    for (int r = 0; r < 4; r++) {
      float mn = fmaxf(mrow[r], pm[r]);
      corr[r] = __expf(mrow[r] - mn);
      mrow[r] = mn;
      rs[r] = 0.f;
    }
#pragma unroll
    for (int nt = 0; nt < 4; nt++)
#pragma unroll
      for (int r = 0; r < 4; r++) {
        float p = __expf(s[nt][r] - mrow[r]);
        s[nt][r] = p;
        rs[r] += p;
      }
#pragma unroll
    for (int r = 0; r < 4; r++) {
      rs[r] += __shfl_xor(rs[r], 1);
      rs[r] += __shfl_xor(rs[r], 2);
      rs[r] += __shfl_xor(rs[r], 4);
      rs[r] += __shfl_xor(rs[r], 8);
      lrow[r] = lrow[r] * corr[r] + rs[r];
    }
#pragma unroll
    for (int nt = 0; nt < 4; nt++)
#pragma unroll
      for (int r = 0; r < 4; r++) o[nt][r] = o[nt][r] * corr[r];

#pragma unroll
    for (int nt = 0; nt < 4; nt++)
#pragma unroll
      for (int r = 0; r < 4; r++)
        Pls[wave][(hi * 4 + r) * 64 + nt * 16 + low] = f2bf(s[nt][r]);
    asm volatile("s_waitcnt lgkmcnt(0)" ::: "memory");

    bf16x8 pa0 = *(const bf16x8*)(&Pls[wave][low * 64 + hi * 8]);
    bf16x8 pa1 = *(const bf16x8*)(&Pls[wave][low * 64 + 32 + hi * 8]);
#pragma unroll
    for (int nt = 0; nt < 4; nt++) {
      bf16x8 v0 = *(const bf16x8*)(Vls + (nt * 16 + low) * 64 + hi * 8);
      bf16x8 v1 = *(const bf16x8*)(Vls + (nt * 16 + low) * 64 + 32 + hi * 8);
      o[nt] = mfma16(pa0, v0, o[nt]);
      o[nt] = mfma16(pa1, v1, o[nt]);
    }
  }

  const int b = bh >> 4, h = bh & 15;
#pragma unroll
  for (int nt = 0; nt < 4; nt++)
#pragma unroll
    for (int r = 0; r < 4; r++) {
      int qg = qb + wave * 16 + hi * 4 + r;
      float val = o[nt][r] / lrow[r];
      ctx[((size_t)(b * 2048 + qg)) * 1024 + h * 64 + nt * 16 + low] = f2bf(val);
    }
}

// ---------------- launch ----------------

extern "C" void kernel_launch(void* const* d_in, const int* in_sizes, int n_in,
                              void* d_out, int out_size, void* d_ws, size_t ws_size,
                              hipStream_t stream) {
  const float* x  = (const float*)d_in[0];
  const float* Wq = (const float*)d_in[1];
  const float* bq = (const float*)d_in[2];
  const float* Wk = (const float*)d_in[3];
  const float* bk = (const float*)d_in[4];
  const float* Wv = (const float*)d_in[5];
  const float* bv = (const float*)d_in[6];
  const float* Wo = (const float*)d_in[7];
  const float* bo = (const float*)d_in[8];

  char* ws = (char*)d_ws;
  u16* xb  = (u16*)(ws);                    // [4096][1024] bf16, 8MB
  u16* wT  = (u16*)(ws + (8u << 20));       // 4 x [1024][1024] bf16, 8MB
  u16* qs  = (u16*)(ws + (16u << 20));      // [32][2048][64] bf16, 8MB
  u16* ks  = (u16*)(ws + (24u << 20));      // [32][2048][64] bf16, 8MB
  u16* vts = (u16*)(ws + (32u << 20));      // [32][64][2048] bf16, 8MB
  u16* ctx = (u16*)(ws + (40u << 20));      // [4096][1024] bf16, 8MB

  x_cvt_kernel<<<4096, 256, 0, stream>>>(x, xb);
  wt_cvt_kernel<<<dim3(16, 16, 4), 256, 0, stream>>>(Wq, Wk, Wv, Wo, wT);
  gemm_qkv_kernel<<<dim3(8, 32, 3), 256, 0, stream>>>(xb, wT, bq, bk, bv, qs, ks, vts);
  flash_kernel<<<dim3(32, 32), 256, 0, stream>>>(qs, ks, vts, ctx);
  gemm_out_kernel<<<dim3(8, 32), 256, 0, stream>>>(ctx, wT + 3 * (1u << 20), bo, (float*)d_out);
}

// Round 2
// 142.987 us; speedup vs baseline: 1.5820x; 1.5820x over previous
//
#include <hip/hip_runtime.h>
#include <stdint.h>

typedef unsigned short u16;
typedef __attribute__((ext_vector_type(8))) __bf16 bf16x8;
typedef __attribute__((ext_vector_type(4))) float f32x4;

#define BM 128
#define BN 128
#define BK 32

__device__ __forceinline__ u16 f2bf(float f) {
  union { float f; uint32_t u; } c; c.f = f;
  uint32_t u = c.u + 0x7fffu + ((c.u >> 16) & 1u);
  return (u16)(u >> 16);
}
__device__ __forceinline__ uint32_t pk2(float a, float b) {
  return (uint32_t)f2bf(a) | ((uint32_t)f2bf(b) << 16);
}

__device__ __forceinline__ void async16(const u16* g, u16* l) {
  __builtin_amdgcn_global_load_lds(
      (const __attribute__((address_space(1))) void*)g,
      (__attribute__((address_space(3))) void*)l, 16, 0, 0);
}

__device__ __forceinline__ f32x4 mfma16(bf16x8 a, bf16x8 b, f32x4 c) {
  return __builtin_amdgcn_mfma_f32_16x16x32_bf16(a, b, c, 0, 0, 0);
}

// ---------------- conversion kernels ----------------

__global__ __launch_bounds__(256) void x_cvt_kernel(const float* __restrict__ x,
                                                    u16* __restrict__ xb) {
  int i = (blockIdx.x * 256 + threadIdx.x) * 4;
  float4 v = *(const float4*)(x + i);
  uint2 t; t.x = pk2(v.x, v.y); t.y = pk2(v.z, v.w);
  *(uint2*)(xb + i) = t;
}

// W [K=1024][N=1024] fp32  ->  WT [N][K] bf16
__global__ __launch_bounds__(256) void wt_cvt_kernel(const float* __restrict__ Wq,
                                                     const float* __restrict__ Wk,
                                                     const float* __restrict__ Wv,
                                                     const float* __restrict__ Wo,
                                                     u16* __restrict__ out) {
  __shared__ __align__(16) u16 t[64][72];
  int z = blockIdx.z;
  const float* W = (z == 0) ? Wq : (z == 1) ? Wk : (z == 2) ? Wv : Wo;
  u16* o = out + (size_t)z * (1u << 20);
  int n0 = blockIdx.x * 64, k0 = blockIdx.y * 64;
  int tid = threadIdx.x;
  int c4 = (tid & 15) * 4, r0 = tid >> 4;
#pragma unroll
  for (int i = 0; i < 4; i++) {
    int r = r0 + i * 16;
    float4 v = *(const float4*)(W + (size_t)(k0 + r) * 1024 + n0 + c4);
    t[c4 + 0][r] = f2bf(v.x);
    t[c4 + 1][r] = f2bf(v.y);
    t[c4 + 2][r] = f2bf(v.z);
    t[c4 + 3][r] = f2bf(v.w);
  }
  __syncthreads();
  int n = tid >> 2, kc = (tid & 3) * 16;
  uint4 a = *(const uint4*)&t[n][kc];
  uint4 b = *(const uint4*)&t[n][kc + 8];
  *(uint4*)(o + (size_t)(n0 + n) * 1024 + k0 + kc) = a;
  *(uint4*)(o + (size_t)(n0 + n) * 1024 + k0 + kc + 8) = b;
}

// ---------------- GEMM core (A [M][1024] bf16, Bt [N][1024] bf16) ----------------

__device__ __forceinline__ void gemm_core(const u16* __restrict__ A,
                                          const u16* __restrict__ Bt,
                                          u16* As, u16* Bs, f32x4 (&acc)[4][4]) {
  const int tid = threadIdx.x, wave = tid >> 6, lane = tid & 63;
  const int low = lane & 15, hi = lane >> 4;
  const int wm = wave >> 1, wn = wave & 1;
  const int m0 = blockIdx.y * BM, n0 = blockIdx.x * BN;
  const f32x4 fzero = {0.f, 0.f, 0.f, 0.f};
#pragma unroll
  for (int i = 0; i < 4; i++)
#pragma unroll
    for (int j = 0; j < 4; j++) acc[i][j] = fzero;

  const u16* ap = As + (wm * 64 + low) * BK + hi * 8;
  const u16* bp = Bs + (wn * 64 + low) * BK + hi * 8;

  const int e0 = wave * 128 + lane;
  const int e1 = e0 + 64;
  const u16* ga0 = A + (size_t)(m0 + (e0 >> 2)) * 1024 + (e0 & 3) * 8;
  const u16* ga1 = A + (size_t)(m0 + (e1 >> 2)) * 1024 + (e1 & 3) * 8;
  const u16* gb0 = Bt + (size_t)(n0 + (e0 >> 2)) * 1024 + (e0 & 3) * 8;
  const u16* gb1 = Bt + (size_t)(n0 + (e1 >> 2)) * 1024 + (e1 & 3) * 8;
  u16* la0 = As + (wave * 2 + 0) * 512;
  u16* la1 = As + (wave * 2 + 1) * 512;
  u16* lb0 = Bs + (wave * 2 + 0) * 512;
  u16* lb1 = Bs + (wave * 2 + 1) * 512;

  for (int kt = 0; kt < 1024; kt += BK) {
    __syncthreads();
    async16(ga0 + kt, la0);
    async16(ga1 + kt, la1);
    async16(gb0 + kt, lb0);
    async16(gb1 + kt, lb1);
    __syncthreads();
    bf16x8 af[4], bfv[4];
#pragma unroll
    for (int i = 0; i < 4; i++) af[i] = *(const bf16x8*)(ap + i * 16 * BK);
#pragma unroll
    for (int j = 0; j < 4; j++) bfv[j] = *(const bf16x8*)(bp + j * 16 * BK);
#pragma unroll
    for (int i = 0; i < 4; i++)
#pragma unroll
      for (int j = 0; j < 4; j++) acc[i][j] = mfma16(af[i], bfv[j], acc[i][j]);
  }
}

// QKV projection: out layouts  Q,K -> [BH][L][64],  V -> [BH][64][L]
// Q is pre-scaled by 0.125 (1/sqrt(HD)).
__global__ __launch_bounds__(256) void gemm_qkv_kernel(
    const u16* __restrict__ xb, const u16* __restrict__ wT,
    const float* __restrict__ bq, const float* __restrict__ bk,
    const float* __restrict__ bv,
    u16* __restrict__ qs, u16* __restrict__ ks, u16* __restrict__ vts) {
  __shared__ __align__(16) u16 As[BM * BK];
  __shared__ __align__(16) u16 Bs[BN * BK];
  const int z = blockIdx.z;
  const u16* Bt = wT + (size_t)z * (1u << 20);
  f32x4 acc[4][4];
  gemm_core(xb, Bt, As, Bs, acc);

  const float* bias = (z == 0) ? bq : (z == 1) ? bk : bv;
  u16* out = (z == 0) ? qs : (z == 1) ? ks : vts;
  const float scale = (z == 0) ? 0.125f : 1.0f;
  const int tid = threadIdx.x, wave = tid >> 6, lane = tid & 63;
  const int low = lane & 15, hi = lane >> 4;
  const int wm = wave >> 1, wn = wave & 1;
  const int m0 = blockIdx.y * BM, n0 = blockIdx.x * BN;
#pragma unroll
  for (int i = 0; i < 4; i++)
#pragma unroll
    for (int j = 0; j < 4; j++) {
      int gn = n0 + wn * 64 + j * 16 + low;
      float bval = bias[gn];
      int h = gn >> 6, hd = gn & 63;
#pragma unroll
      for (int r = 0; r < 4; r++) {
        int gm = m0 + wm * 64 + i * 16 + hi * 4 + r;
        int b = gm >> 11, l = gm & 2047;
        float v = (acc[i][j][r] + bval) * scale;
        size_t addr;
        if (z == 2) addr = ((size_t)((b * 16 + h) * 64 + hd)) * 2048 + l;
        else        addr = ((size_t)((b * 16 + h) * 2048 + l)) * 64 + hd;
        out[addr] = f2bf(v);
      }
    }
}

// output projection: ctx[M][1024] @ WoT + bo -> fp32 out[M][1024]
__global__ __launch_bounds__(256) void gemm_out_kernel(
    const u16* __restrict__ ctx, const u16* __restrict__ woT,
    const float* __restrict__ bo, float* __restrict__ out) {
  __shared__ __align__(16) u16 As[BM * BK];
  __shared__ __align__(16) u16 Bs[BN * BK];
  f32x4 acc[4][4];
  gemm_core(ctx, woT, As, Bs, acc);
  const int tid = threadIdx.x, wave = tid >> 6, lane = tid & 63;
  const int low = lane & 15, hi = lane >> 4;
  const int wm = wave >> 1, wn = wave & 1;
  const int m0 = blockIdx.y * BM, n0 = blockIdx.x * BN;
#pragma unroll
  for (int i = 0; i < 4; i++)
#pragma unroll
    for (int j = 0; j < 4; j++) {
      int gn = n0 + wn * 64 + j * 16 + low;
      float bval = bo[gn];
#pragma unroll
      for (int r = 0; r < 4; r++) {
        int gm = m0 + wm * 64 + i * 16 + hi * 4 + r;
        out[(size_t)gm * 1024 + gn] = acc[i][j][r] + bval;
      }
    }
}

// ---------------- flash attention v2 ----------------
// 1D grid of 512 blocks: qt = 15 - (bid>>5) (LPT heavy-first), bh = bid&31.
// 4 waves x 32 q rows = 128 q rows/block. KV tiles of 64, double-buffered,
// XOR-chunk-swizzled LDS (cc ^= row&7), staged via pre-swizzled global src.
// Swapped QK^T (mfma(K,Q)) -> lane holds P[q=low][k=16nt+4hi+r]; P goes
// through a padded (stride 72) per-wave LDS buffer: 8 b64 writes + 4 b128
// reads, conflict-free. One raw barrier + vmcnt(0) per tile.
#define PSTR 72

__global__ __launch_bounds__(256) void flash_kernel(
    const u16* __restrict__ Qs, const u16* __restrict__ Ks,
    const u16* __restrict__ Vts, u16* __restrict__ ctx) {
  __shared__ __align__(16) u16 Kls[2][64 * 64];
  __shared__ __align__(16) u16 Vls[2][64 * 64];
  __shared__ __align__(16) u16 Pls[8][16 * PSTR];

  const int bid = blockIdx.x;
  const int qt = 15 - (bid >> 5);
  const int bh = bid & 31;
  const int qb = qt * 128;
  const int nkv = 2 * qt + 2;

  const int tid = threadIdx.x, wave = tid >> 6, lane = tid & 63;
  const int low = lane & 15, hi = lane >> 4;
  const int x7 = low & 7;

  const u16* Qb = Qs + (size_t)bh * (2048 * 64);
  const u16* Kb = Ks + (size_t)bh * (2048 * 64);
  const u16* Vb = Vts + (size_t)bh * (64 * 2048);
  const f32x4 fzero = {0.f, 0.f, 0.f, 0.f};

  // Q fragments (already scaled by 0.125): qf[sub][dhalf]
  bf16x8 qf[2][2];
#pragma unroll
  for (int sub = 0; sub < 2; sub++)
#pragma unroll
    for (int dh = 0; dh < 2; dh++)
      qf[sub][dh] = *(const bf16x8*)(Qb + (size_t)(qb + wave * 32 + sub * 16 + low) * 64 + dh * 32 + hi * 8);

  f32x4 o[2][4];
  float m_[2], l_[2];
#pragma unroll
  for (int sub = 0; sub < 2; sub++) {
    m_[sub] = -1e30f; l_[sub] = 0.f;
#pragma unroll
    for (int nt = 0; nt < 4; nt++) o[sub][nt] = fzero;
  }

  // staging geometry
  const int srow0 = (lane >> 3);  // 0..7 within the 8-row chunk group
  const int scc = lane & 7;

#define STAGE(buf, KT0)                                                        \
  {                                                                            \
    _Pragma("unroll") for (int i = 0; i < 2; i++) {                            \
      int row = (wave * 2 + i) * 8 + srow0;                                    \
      async16(Kb + (size_t)((KT0) + row) * 64 + ((scc ^ (row & 7)) * 8),       \
              &Kls[buf][(wave * 2 + i) * 512]);                                \
      async16(Vb + (size_t)row * 2048 + (KT0) + ((scc ^ (row & 7)) * 8),       \
              &Vls[buf][(wave * 2 + i) * 512]);                                \
    }                                                                          \
  }

  STAGE(0, 0)
  asm volatile("s_waitcnt vmcnt(0)" ::: "memory");
  __builtin_amdgcn_s_barrier();

  u16* pls0 = &Pls[wave * 2 + 0][0];
  u16* pls1 = &Pls[wave * 2 + 1][0];

  int cur = 0;
  for (int t = 0; t < nkv; t++) {
    const int kt0 = t * 64;
    if (t + 1 < nkv) STAGE(cur ^ 1, kt0 + 64)

    const u16* Kc = &Kls[cur][0];
    const u16* Vc = &Vls[cur][0];

    // ---- QK^T (swapped: A=K rows k, B=Q rows q) ----
    f32x4 s[2][4];
#pragma unroll
    for (int nt = 0; nt < 4; nt++) {
      const u16* kb = Kc + (nt * 16 + low) * 64;
      bf16x8 kf0 = *(const bf16x8*)(kb + ((hi ^ x7) * 8));
      bf16x8 kf1 = *(const bf16x8*)(kb + (((4 + hi) ^ x7) * 8));
      s[0][nt] = mfma16(kf0, qf[0][0], fzero);
      s[0][nt] = mfma16(kf1, qf[0][1], s[0][nt]);
      s[1][nt] = mfma16(kf0, qf[1][0], fzero);
      s[1][nt] = mfma16(kf1, qf[1][1], s[1][nt]);
    }

    // ---- softmax (per sub; lane owns q = low, 16 k values) ----
#pragma unroll
    for (int sub = 0; sub < 2; sub++) {
      const int qsb = qb + wave * 32 + sub * 16;
      const int qrow = qsb + low;
      if (kt0 + 63 > qsb) {
#pragma unroll
        for (int nt = 0; nt < 4; nt++)
#pragma unroll
          for (int r = 0; r < 4; r++) {
            int kg = kt0 + nt * 16 + hi * 4 + r;
            if (kg > qrow) s[sub][nt][r] = -1e30f;
          }
      }
      float pm = -1e30f;
#pragma unroll
      for (int nt = 0; nt < 4; nt++)
#pragma unroll
        for (int r = 0; r < 4; r++) pm = fmaxf(pm, s[sub][nt][r]);
      pm = fmaxf(pm, __shfl_xor(pm, 16));
      pm = fmaxf(pm, __shfl_xor(pm, 32));
      float mn = fmaxf(m_[sub], pm);
      float corr = __expf(m_[sub] - mn);
      m_[sub] = mn;
      float rs = 0.f;
#pragma unroll
      for (int nt = 0; nt < 4; nt++)
#pragma unroll
        for (int r = 0; r < 4; r++) {
          float p = __expf(s[sub][nt][r] - mn);
          s[sub][nt][r] = p;
          rs += p;
        }
      rs += __shfl_xor(rs, 16);
      rs += __shfl_xor(rs, 32);
      l_[sub] = l_[sub] * corr + rs;
#pragma unroll
      for (int nt = 0; nt < 4; nt++) {
        o[sub][nt][0] *= corr; o[sub][nt][1] *= corr;
        o[sub][nt][2] *= corr; o[sub][nt][3] *= corr;
      }
      // P write: [16 q][64 k], stride 72, b64 packed (4 contiguous k)
      u16* pls = sub ? pls1 : pls0;
#pragma unroll
      for (int nt = 0; nt < 4; nt++) {
        uint2 w;
        w.x = pk2(s[sub][nt][0], s[sub][nt][1]);
        w.y = pk2(s[sub][nt][2], s[sub][nt][3]);
        *(uint2*)(pls + low * PSTR + nt * 16 + hi * 4) = w;
      }
    }
    asm volatile("s_waitcnt lgkmcnt(0)" ::: "memory");
    __builtin_amdgcn_sched_barrier(0);

    // ---- PV (A = V^T rows d, B = P rows q) ----
    bf16x8 pb[2][2];
#pragma unroll
    for (int kc = 0; kc < 2; kc++) {
      pb[0][kc] = *(const bf16x8*)(pls0 + low * PSTR + kc * 32 + hi * 8);
      pb[1][kc] = *(const bf16x8*)(pls1 + low * PSTR + kc * 32 + hi * 8);
    }
#pragma unroll
    for (int ntd = 0; ntd < 4; ntd++) {
      const u16* vb = Vc + (ntd * 16 + low) * 64;
      bf16x8 vf0 = *(const bf16x8*)(vb + ((hi ^ x7) * 8));
      bf16x8 vf1 = *(const bf16x8*)(vb + (((4 + hi) ^ x7) * 8));
      o[0][ntd] = mfma16(vf0, pb[0][0], o[0][ntd]);
      o[0][ntd] = mfma16(vf1, pb[0][1], o[0][ntd]);
      o[1][ntd] = mfma16(vf0, pb[1][0], o[1][ntd]);
      o[1][ntd] = mfma16(vf1, pb[1][1], o[1][ntd]);
    }

    asm volatile("s_waitcnt vmcnt(0)" ::: "memory");
    __builtin_amdgcn_s_barrier();
    cur ^= 1;
  }

  // ---- epilogue: O[q=low][d = ntd*16 + hi*4 + r] / l ----
  const int b = bh >> 4, h = bh & 15;
#pragma unroll
  for (int sub = 0; sub < 2; sub++) {
    float inv = 1.f / l_[sub];
    int qg = qb + wave * 32 + sub * 16 + low;
    size_t base = ((size_t)(b * 2048 + qg)) * 1024 + h * 64;
#pragma unroll
    for (int ntd = 0; ntd < 4; ntd++) {
      uint2 w;
      w.x = pk2(o[sub][ntd][0] * inv, o[sub][ntd][1] * inv);
      w.y = pk2(o[sub][ntd][2] * inv, o[sub][ntd][3] * inv);
      *(uint2*)(ctx + base + ntd * 16 + hi * 4) = w;
    }
  }
}

// ---------------- launch ----------------

extern "C" void kernel_launch(void* const* d_in, const int* in_sizes, int n_in,
                              void* d_out, int out_size, void* d_ws, size_t ws_size,
                              hipStream_t stream) {
  const float* x  = (const float*)d_in[0];
  const float* Wq = (const float*)d_in[1];
  const float* bq = (const float*)d_in[2];
  const float* Wk = (const float*)d_in[3];
  const float* bk = (const float*)d_in[4];
  const float* Wv = (const float*)d_in[5];
  const float* bv = (const float*)d_in[6];
  const float* Wo = (const float*)d_in[7];
  const float* bo = (const float*)d_in[8];

  char* ws = (char*)d_ws;
  u16* xb  = (u16*)(ws);                    // [4096][1024] bf16, 8MB
  u16* wT  = (u16*)(ws + (8u << 20));       // 4 x [1024][1024] bf16, 8MB
  u16* qs  = (u16*)(ws + (16u << 20));      // [32][2048][64] bf16, 8MB (pre-scaled)
  u16* ks  = (u16*)(ws + (24u << 20));      // [32][2048][64] bf16, 8MB
  u16* vts = (u16*)(ws + (32u << 20));      // [32][64][2048] bf16, 8MB
  u16* ctx = (u16*)(ws + (40u << 20));      // [4096][1024] bf16, 8MB

  x_cvt_kernel<<<4096, 256, 0, stream>>>(x, xb);
  wt_cvt_kernel<<<dim3(16, 16, 4), 256, 0, stream>>>(Wq, Wk, Wv, Wo, wT);
  gemm_qkv_kernel<<<dim3(8, 32, 3), 256, 0, stream>>>(xb, wT, bq, bk, bv, qs, ks, vts);
  flash_kernel<<<512, 256, 0, stream>>>(qs, ks, vts, ctx);
  gemm_out_kernel<<<dim3(8, 32), 256, 0, stream>>>(ctx, wT + 3 * (1u << 20), bo, (float*)d_out);
}

// Round 3
// 133.340 us; speedup vs baseline: 1.6964x; 1.0723x over previous
//
#include <hip/hip_runtime.h>
#include <stdint.h>

typedef unsigned short u16;
typedef __attribute__((ext_vector_type(8))) __bf16 bf16x8;
typedef __attribute__((ext_vector_type(4))) float f32x4;

#define BM 128
#define BN 128
#define BK 32

__device__ __forceinline__ u16 f2bf(float f) {
  union { float f; uint32_t u; } c; c.f = f;
  uint32_t u = c.u + 0x7fffu + ((c.u >> 16) & 1u);
  return (u16)(u >> 16);
}
__device__ __forceinline__ uint32_t cvtpk(float a, float b) {
  uint32_t r;
  asm("v_cvt_pk_bf16_f32 %0, %1, %2" : "=v"(r) : "v"(a), "v"(b));
  return r;
}

__device__ __forceinline__ void async16(const u16* g, u16* l) {
  __builtin_amdgcn_global_load_lds(
      (const __attribute__((address_space(1))) void*)g,
      (__attribute__((address_space(3))) void*)l, 16, 0, 0);
}

__device__ __forceinline__ f32x4 mfma16(bf16x8 a, bf16x8 b, f32x4 c) {
  return __builtin_amdgcn_mfma_f32_16x16x32_bf16(a, b, c, 0, 0, 0);
}

// ---------------- conversion kernels ----------------

__global__ __launch_bounds__(256) void x_cvt_kernel(const float* __restrict__ x,
                                                    u16* __restrict__ xb) {
  int i = (blockIdx.x * 256 + threadIdx.x) * 4;
  float4 v = *(const float4*)(x + i);
  uint2 t; t.x = cvtpk(v.x, v.y); t.y = cvtpk(v.z, v.w);
  *(uint2*)(xb + i) = t;
}

// W [K=1024][N=1024] fp32  ->  WT [N][K] bf16
__global__ __launch_bounds__(256) void wt_cvt_kernel(const float* __restrict__ Wq,
                                                     const float* __restrict__ Wk,
                                                     const float* __restrict__ Wv,
                                                     const float* __restrict__ Wo,
                                                     u16* __restrict__ out) {
  __shared__ __align__(16) u16 t[64][72];
  int z = blockIdx.z;
  const float* W = (z == 0) ? Wq : (z == 1) ? Wk : (z == 2) ? Wv : Wo;
  u16* o = out + (size_t)z * (1u << 20);
  int n0 = blockIdx.x * 64, k0 = blockIdx.y * 64;
  int tid = threadIdx.x;
  int c4 = (tid & 15) * 4, r0 = tid >> 4;
#pragma unroll
  for (int i = 0; i < 4; i++) {
    int r = r0 + i * 16;
    float4 v = *(const float4*)(W + (size_t)(k0 + r) * 1024 + n0 + c4);
    t[c4 + 0][r] = f2bf(v.x);
    t[c4 + 1][r] = f2bf(v.y);
    t[c4 + 2][r] = f2bf(v.z);
    t[c4 + 3][r] = f2bf(v.w);
  }
  __syncthreads();
  int n = tid >> 2, kc = (tid & 3) * 16;
  uint4 a = *(const uint4*)&t[n][kc];
  uint4 b = *(const uint4*)&t[n][kc + 8];
  *(uint4*)(o + (size_t)(n0 + n) * 1024 + k0 + kc) = a;
  *(uint4*)(o + (size_t)(n0 + n) * 1024 + k0 + kc + 8) = b;
}

// ---------------- GEMM core (A [M][1024] bf16, Bt [N][1024] bf16) ----------------

__device__ __forceinline__ void gemm_core(const u16* __restrict__ A,
                                          const u16* __restrict__ Bt,
                                          u16* As, u16* Bs, f32x4 (&acc)[4][4]) {
  const int tid = threadIdx.x, wave = tid >> 6, lane = tid & 63;
  const int low = lane & 15, hi = lane >> 4;
  const int wm = wave >> 1, wn = wave & 1;
  const int m0 = blockIdx.y * BM, n0 = blockIdx.x * BN;
  const f32x4 fzero = {0.f, 0.f, 0.f, 0.f};
#pragma unroll
  for (int i = 0; i < 4; i++)
#pragma unroll
    for (int j = 0; j < 4; j++) acc[i][j] = fzero;

  const u16* ap = As + (wm * 64 + low) * BK + hi * 8;
  const u16* bp = Bs + (wn * 64 + low) * BK + hi * 8;

  const int e0 = wave * 128 + lane;
  const int e1 = e0 + 64;
  const u16* ga0 = A + (size_t)(m0 + (e0 >> 2)) * 1024 + (e0 & 3) * 8;
  const u16* ga1 = A + (size_t)(m0 + (e1 >> 2)) * 1024 + (e1 & 3) * 8;
  const u16* gb0 = Bt + (size_t)(n0 + (e0 >> 2)) * 1024 + (e0 & 3) * 8;
  const u16* gb1 = Bt + (size_t)(n0 + (e1 >> 2)) * 1024 + (e1 & 3) * 8;
  u16* la0 = As + (wave * 2 + 0) * 512;
  u16* la1 = As + (wave * 2 + 1) * 512;
  u16* lb0 = Bs + (wave * 2 + 0) * 512;
  u16* lb1 = Bs + (wave * 2 + 1) * 512;

  for (int kt = 0; kt < 1024; kt += BK) {
    __syncthreads();
    async16(ga0 + kt, la0);
    async16(ga1 + kt, la1);
    async16(gb0 + kt, lb0);
    async16(gb1 + kt, lb1);
    __syncthreads();
    bf16x8 af[4], bfv[4];
#pragma unroll
    for (int i = 0; i < 4; i++) af[i] = *(const bf16x8*)(ap + i * 16 * BK);
#pragma unroll
    for (int j = 0; j < 4; j++) bfv[j] = *(const bf16x8*)(bp + j * 16 * BK);
#pragma unroll
    for (int i = 0; i < 4; i++)
#pragma unroll
      for (int j = 0; j < 4; j++) acc[i][j] = mfma16(af[i], bfv[j], acc[i][j]);
  }
}

// QKV projection: out layouts  Q,K -> [BH][L][64],  V -> [BH][64][L]
// Q is pre-scaled by 0.125 * log2(e) (exp2-domain softmax downstream).
__global__ __launch_bounds__(256) void gemm_qkv_kernel(
    const u16* __restrict__ xb, const u16* __restrict__ wT,
    const float* __restrict__ bq, const float* __restrict__ bk,
    const float* __restrict__ bv,
    u16* __restrict__ qs, u16* __restrict__ ks, u16* __restrict__ vts) {
  __shared__ __align__(16) u16 As[BM * BK];
  __shared__ __align__(16) u16 Bs[BN * BK];
  const int z = blockIdx.z;
  const u16* Bt = wT + (size_t)z * (1u << 20);
  f32x4 acc[4][4];
  gemm_core(xb, Bt, As, Bs, acc);

  const float* bias = (z == 0) ? bq : (z == 1) ? bk : bv;
  u16* out = (z == 0) ? qs : (z == 1) ? ks : vts;
  const float scale = (z == 0) ? 0.180336880f : 1.0f;  // 0.125 * log2(e)
  const int tid = threadIdx.x, wave = tid >> 6, lane = tid & 63;
  const int low = lane & 15, hi = lane >> 4;
  const int wm = wave >> 1, wn = wave & 1;
  const int m0 = blockIdx.y * BM, n0 = blockIdx.x * BN;
#pragma unroll
  for (int i = 0; i < 4; i++)
#pragma unroll
    for (int j = 0; j < 4; j++) {
      int gn = n0 + wn * 64 + j * 16 + low;
      float bval = bias[gn];
      int h = gn >> 6, hd = gn & 63;
#pragma unroll
      for (int r = 0; r < 4; r++) {
        int gm = m0 + wm * 64 + i * 16 + hi * 4 + r;
        int b = gm >> 11, l = gm & 2047;
        float v = (acc[i][j][r] + bval) * scale;
        size_t addr;
        if (z == 2) addr = ((size_t)((b * 16 + h) * 64 + hd)) * 2048 + l;
        else        addr = ((size_t)((b * 16 + h) * 2048 + l)) * 64 + hd;
        out[addr] = f2bf(v);
      }
    }
}

// output projection: ctx[M][1024] @ WoT + bo -> fp32 out[M][1024]
__global__ __launch_bounds__(256) void gemm_out_kernel(
    const u16* __restrict__ ctx, const u16* __restrict__ woT,
    const float* __restrict__ bo, float* __restrict__ out) {
  __shared__ __align__(16) u16 As[BM * BK];
  __shared__ __align__(16) u16 Bs[BN * BK];
  f32x4 acc[4][4];
  gemm_core(ctx, woT, As, Bs, acc);
  const int tid = threadIdx.x, wave = tid >> 6, lane = tid & 63;
  const int low = lane & 15, hi = lane >> 4;
  const int wm = wave >> 1, wn = wave & 1;
  const int m0 = blockIdx.y * BM, n0 = blockIdx.x * BN;
#pragma unroll
  for (int i = 0; i < 4; i++)
#pragma unroll
    for (int j = 0; j < 4; j++) {
      int gn = n0 + wn * 64 + j * 16 + low;
      float bval = bo[gn];
#pragma unroll
      for (int r = 0; r < 4; r++) {
        int gm = m0 + wm * 64 + i * 16 + hi * 4 + r;
        out[(size_t)gm * 1024 + gn] = acc[i][j][r] + bval;
      }
    }
}

// ---------------- flash attention v3 ----------------
// 512 blocks: qt = 15 - (bid>>5), bh = bid&31 (bid&7 = bh&7 -> per-XCD KV L2
// affinity). 4 waves x 32 q rows. KV tiles of 64, TRIPLE-buffered, counted
// vmcnt(4) (never drained in-loop), ONE barrier per tile. Swapped QK^T;
// exp2-domain softmax with defer-max (THR=8); V pre-loaded to regs before
// softmax; P via padded per-wave LDS (stride 72).
#define PSTR 72

__global__ __launch_bounds__(256) void flash_kernel(
    const u16* __restrict__ Qs, const u16* __restrict__ Ks,
    const u16* __restrict__ Vts, u16* __restrict__ ctx) {
  __shared__ __align__(16) u16 Kls[3][64 * 64];
  __shared__ __align__(16) u16 Vls[3][64 * 64];
  __shared__ __align__(16) u16 Pls[8][16 * PSTR];

  const int bid = blockIdx.x;
  const int qt = 15 - (bid >> 5);
  const int bh = bid & 31;
  const int qb = qt * 128;
  const int nkv = 2 * qt + 2;

  const int tid = threadIdx.x, wave = tid >> 6, lane = tid & 63;
  const int low = lane & 15, hi = lane >> 4;
  const int x7 = low & 7;

  const u16* Qb = Qs + (size_t)bh * (2048 * 64);
  const u16* Kb = Ks + (size_t)bh * (2048 * 64);
  const u16* Vb = Vts + (size_t)bh * (64 * 2048);
  const f32x4 fzero = {0.f, 0.f, 0.f, 0.f};

  // Q fragments (pre-scaled by 0.125*log2e): qf[sub][dhalf]
  bf16x8 qf[2][2];
#pragma unroll
  for (int sub = 0; sub < 2; sub++)
#pragma unroll
    for (int dh = 0; dh < 2; dh++)
      qf[sub][dh] = *(const bf16x8*)(Qb + (size_t)(qb + wave * 32 + sub * 16 + low) * 64 + dh * 32 + hi * 8);

  f32x4 o[2][4];
  float m_[2], l_[2];
#pragma unroll
  for (int sub = 0; sub < 2; sub++) {
    m_[sub] = -1e30f; l_[sub] = 0.f;
#pragma unroll
    for (int nt = 0; nt < 4; nt++) o[sub][nt] = fzero;
  }

  const int srow0 = (lane >> 3);
  const int scc = lane & 7;

#define STAGE(buf, KT0)                                                        \
  {                                                                            \
    _Pragma("unroll") for (int i = 0; i < 2; i++) {                            \
      int row = (wave * 2 + i) * 8 + srow0;                                    \
      async16(Kb + (size_t)((KT0) + row) * 64 + ((scc ^ (row & 7)) * 8),       \
              &Kls[buf][(wave * 2 + i) * 512]);                                \
      async16(Vb + (size_t)row * 2048 + (KT0) + ((scc ^ (row & 7)) * 8),       \
              &Vls[buf][(wave * 2 + i) * 512]);                                \
    }                                                                          \
  }

  STAGE(0, 0)
  STAGE(1, 64)

  u16* pls0 = &Pls[wave * 2 + 0][0];
  u16* pls1 = &Pls[wave * 2 + 1][0];
  const int qmax = qb + wave * 32 + 31;  // highest q row of this wave

  int c0 = 0, c1 = 1, c2 = 2;
  for (int t = 0; t < nkv; t++) {
    const int kt0 = t * 64;
    if (t + 1 < nkv) { asm volatile("s_waitcnt vmcnt(4)" ::: "memory"); }
    else             { asm volatile("s_waitcnt vmcnt(0)" ::: "memory"); }
    __builtin_amdgcn_s_barrier();
    if (t + 2 < nkv) STAGE(c2, kt0 + 128)

    if (kt0 <= qmax) {
      const u16* Kc = &Kls[c0][0];
      const u16* Vc = &Vls[c0][0];

      // ---- QK^T (swapped: A=K rows k, B=Q rows q) ----
      f32x4 s[2][4];
      __builtin_amdgcn_s_setprio(1);
#pragma unroll
      for (int nt = 0; nt < 4; nt++) {
        const u16* kb = Kc + (nt * 16 + low) * 64;
        bf16x8 kf0 = *(const bf16x8*)(kb + ((hi ^ x7) * 8));
        bf16x8 kf1 = *(const bf16x8*)(kb + (((4 + hi) ^ x7) * 8));
        s[0][nt] = mfma16(kf0, qf[0][0], fzero);
        s[0][nt] = mfma16(kf1, qf[0][1], s[0][nt]);
        s[1][nt] = mfma16(kf0, qf[1][0], fzero);
        s[1][nt] = mfma16(kf1, qf[1][1], s[1][nt]);
      }
      __builtin_amdgcn_s_setprio(0);

      // ---- V fragments to regs early (overlap with softmax) ----
      bf16x8 vf[4][2];
#pragma unroll
      for (int ntd = 0; ntd < 4; ntd++) {
        const u16* vb = Vc + (ntd * 16 + low) * 64;
        vf[ntd][0] = *(const bf16x8*)(vb + ((hi ^ x7) * 8));
        vf[ntd][1] = *(const bf16x8*)(vb + (((4 + hi) ^ x7) * 8));
      }

      // ---- mask (diagonal tiles only) ----
#pragma unroll
      for (int sub = 0; sub < 2; sub++) {
        const int qsb = qb + wave * 32 + sub * 16;
        if (kt0 + 63 > qsb) {
          const int qrow = qsb + low;
#pragma unroll
          for (int nt = 0; nt < 4; nt++)
#pragma unroll
            for (int r = 0; r < 4; r++) {
              int kg = kt0 + nt * 16 + hi * 4 + r;
              if (kg > qrow) s[sub][nt][r] = -1e30f;
            }
        }
      }

      // ---- tile max + defer-max decision ----
      float pm[2];
#pragma unroll
      for (int sub = 0; sub < 2; sub++) {
        float p = -1e30f;
#pragma unroll
        for (int nt = 0; nt < 4; nt++)
#pragma unroll
          for (int r = 0; r < 4; r++) p = fmaxf(p, s[sub][nt][r]);
        p = fmaxf(p, __shfl_xor(p, 16));
        p = fmaxf(p, __shfl_xor(p, 32));
        pm[sub] = p;
      }
      if (__any((pm[0] > m_[0] + 8.f) || (pm[1] > m_[1] + 8.f))) {
#pragma unroll
        for (int sub = 0; sub < 2; sub++) {
          float mn = fmaxf(m_[sub], pm[sub]);
          float corr = __builtin_amdgcn_exp2f(m_[sub] - mn);
          m_[sub] = mn;
          l_[sub] *= corr;
#pragma unroll
          for (int nt = 0; nt < 4; nt++) {
            o[sub][nt][0] *= corr; o[sub][nt][1] *= corr;
            o[sub][nt][2] *= corr; o[sub][nt][3] *= corr;
          }
        }
      }

      // ---- exp2 + row-sum + P pack/write ----
#pragma unroll
      for (int sub = 0; sub < 2; sub++) {
        float rs = 0.f;
        u16* pls = sub ? pls1 : pls0;
#pragma unroll
        for (int nt = 0; nt < 4; nt++) {
          float p0 = __builtin_amdgcn_exp2f(s[sub][nt][0] - m_[sub]);
          float p1 = __builtin_amdgcn_exp2f(s[sub][nt][1] - m_[sub]);
          float p2 = __builtin_amdgcn_exp2f(s[sub][nt][2] - m_[sub]);
          float p3 = __builtin_amdgcn_exp2f(s[sub][nt][3] - m_[sub]);
          rs += (p0 + p1) + (p2 + p3);
          uint2 w; w.x = cvtpk(p0, p1); w.y = cvtpk(p2, p3);
          *(uint2*)(pls + low * PSTR + nt * 16 + hi * 4) = w;
        }
        rs += __shfl_xor(rs, 16);
        rs += __shfl_xor(rs, 32);
        l_[sub] += rs;
      }
      asm volatile("s_waitcnt lgkmcnt(0)" ::: "memory");
      __builtin_amdgcn_sched_barrier(0);

      // ---- PV (A = V^T rows d, B = P rows q) ----
      bf16x8 pb[2][2];
#pragma unroll
      for (int kc = 0; kc < 2; kc++) {
        pb[0][kc] = *(const bf16x8*)(pls0 + low * PSTR + kc * 32 + hi * 8);
        pb[1][kc] = *(const bf16x8*)(pls1 + low * PSTR + kc * 32 + hi * 8);
      }
      __builtin_amdgcn_s_setprio(1);
#pragma unroll
      for (int ntd = 0; ntd < 4; ntd++) {
        o[0][ntd] = mfma16(vf[ntd][0], pb[0][0], o[0][ntd]);
        o[0][ntd] = mfma16(vf[ntd][1], pb[0][1], o[0][ntd]);
        o[1][ntd] = mfma16(vf[ntd][0], pb[1][0], o[1][ntd]);
        o[1][ntd] = mfma16(vf[ntd][1], pb[1][1], o[1][ntd]);
      }
      __builtin_amdgcn_s_setprio(0);
    }

    int tmp = c0; c0 = c1; c1 = c2; c2 = tmp;
  }

  // ---- epilogue ----
  const int b = bh >> 4, h = bh & 15;
#pragma unroll
  for (int sub = 0; sub < 2; sub++) {
    float inv = 1.f / l_[sub];
    int qg = qb + wave * 32 + sub * 16 + low;
    size_t base = ((size_t)(b * 2048 + qg)) * 1024 + h * 64;
#pragma unroll
    for (int ntd = 0; ntd < 4; ntd++) {
      uint2 w;
      w.x = cvtpk(o[sub][ntd][0] * inv, o[sub][ntd][1] * inv);
      w.y = cvtpk(o[sub][ntd][2] * inv, o[sub][ntd][3] * inv);
      *(uint2*)(ctx + base + ntd * 16 + hi * 4) = w;
    }
  }
}

// ---------------- launch ----------------

extern "C" void kernel_launch(void* const* d_in, const int* in_sizes, int n_in,
                              void* d_out, int out_size, void* d_ws, size_t ws_size,
                              hipStream_t stream) {
  const float* x  = (const float*)d_in[0];
  const float* Wq = (const float*)d_in[1];
  const float* bq = (const float*)d_in[2];
  const float* Wk = (const float*)d_in[3];
  const float* bk = (const float*)d_in[4];
  const float* Wv = (const float*)d_in[5];
  const float* bv = (const float*)d_in[6];
  const float* Wo = (const float*)d_in[7];
  const float* bo = (const float*)d_in[8];

  char* ws = (char*)d_ws;
  u16* xb  = (u16*)(ws);                    // [4096][1024] bf16, 8MB
  u16* wT  = (u16*)(ws + (8u << 20));       // 4 x [1024][1024] bf16, 8MB
  u16* qs  = (u16*)(ws + (16u << 20));      // [32][2048][64] bf16 (pre-scaled)
  u16* ks  = (u16*)(ws + (24u << 20));      // [32][2048][64] bf16
  u16* vts = (u16*)(ws + (32u << 20));      // [32][64][2048] bf16
  u16* ctx = (u16*)(ws + (40u << 20));      // [4096][1024] bf16

  x_cvt_kernel<<<4096, 256, 0, stream>>>(x, xb);
  wt_cvt_kernel<<<dim3(16, 16, 4), 256, 0, stream>>>(Wq, Wk, Wv, Wo, wT);
  gemm_qkv_kernel<<<dim3(8, 32, 3), 256, 0, stream>>>(xb, wT, bq, bk, bv, qs, ks, vts);
  flash_kernel<<<512, 256, 0, stream>>>(qs, ks, vts, ctx);
  gemm_out_kernel<<<dim3(8, 32), 256, 0, stream>>>(ctx, wT + 3 * (1u << 20), bo, (float*)d_out);
}

// Round 5
// 130.884 us; speedup vs baseline: 1.7283x; 1.0188x over previous
//
#include <hip/hip_runtime.h>
#include <stdint.h>

typedef unsigned short u16;
typedef __attribute__((ext_vector_type(8))) __bf16 bf16x8;
typedef __attribute__((ext_vector_type(4))) float f32x4;
typedef __attribute__((ext_vector_type(16))) float f32x16;

#define BM 128
#define BN 128
#define BK 32

__device__ __forceinline__ u16 f2bf(float f) {
  union { float f; uint32_t u; } c; c.f = f;
  uint32_t u = c.u + 0x7fffu + ((c.u >> 16) & 1u);
  return (u16)(u >> 16);
}
__device__ __forceinline__ uint32_t cvtpk(float a, float b) {
  uint32_t r;
  asm("v_cvt_pk_bf16_f32 %0, %1, %2" : "=v"(r) : "v"(a), "v"(b));
  return r;
}

__device__ __forceinline__ void async16(const u16* g, u16* l) {
  __builtin_amdgcn_global_load_lds(
      (const __attribute__((address_space(1))) void*)g,
      (__attribute__((address_space(3))) void*)l, 16, 0, 0);
}

__device__ __forceinline__ f32x4 mfma16(bf16x8 a, bf16x8 b, f32x4 c) {
  return __builtin_amdgcn_mfma_f32_16x16x32_bf16(a, b, c, 0, 0, 0);
}
__device__ __forceinline__ f32x16 mfma32(bf16x8 a, bf16x8 b, f32x16 c) {
  return __builtin_amdgcn_mfma_f32_32x32x16_bf16(a, b, c, 0, 0, 0);
}

// ---------------- conversion kernels ----------------

__global__ __launch_bounds__(256) void x_cvt_kernel(const float* __restrict__ x,
                                                    u16* __restrict__ xb) {
  int i = (blockIdx.x * 256 + threadIdx.x) * 4;
  float4 v = *(const float4*)(x + i);
  uint2 t; t.x = cvtpk(v.x, v.y); t.y = cvtpk(v.z, v.w);
  *(uint2*)(xb + i) = t;
}

// W [K=1024][N=1024] fp32  ->  WT [N][K] bf16
__global__ __launch_bounds__(256) void wt_cvt_kernel(const float* __restrict__ Wq,
                                                     const float* __restrict__ Wk,
                                                     const float* __restrict__ Wv,
                                                     const float* __restrict__ Wo,
                                                     u16* __restrict__ out) {
  __shared__ __align__(16) u16 t[64][72];
  int z = blockIdx.z;
  const float* W = (z == 0) ? Wq : (z == 1) ? Wk : (z == 2) ? Wv : Wo;
  u16* o = out + (size_t)z * (1u << 20);
  int n0 = blockIdx.x * 64, k0 = blockIdx.y * 64;
  int tid = threadIdx.x;
  int c4 = (tid & 15) * 4, r0 = tid >> 4;
#pragma unroll
  for (int i = 0; i < 4; i++) {
    int r = r0 + i * 16;
    float4 v = *(const float4*)(W + (size_t)(k0 + r) * 1024 + n0 + c4);
    t[c4 + 0][r] = f2bf(v.x);
    t[c4 + 1][r] = f2bf(v.y);
    t[c4 + 2][r] = f2bf(v.z);
    t[c4 + 3][r] = f2bf(v.w);
  }
  __syncthreads();
  int n = tid >> 2, kc = (tid & 3) * 16;
  uint4 a = *(const uint4*)&t[n][kc];
  uint4 b = *(const uint4*)&t[n][kc + 8];
  *(uint4*)(o + (size_t)(n0 + n) * 1024 + k0 + kc) = a;
  *(uint4*)(o + (size_t)(n0 + n) * 1024 + k0 + kc + 8) = b;
}

// ---------------- GEMM core (A [M][1024] bf16, Bt [N][1024] bf16) ----------------

__device__ __forceinline__ void gemm_core(const u16* __restrict__ A,
                                          const u16* __restrict__ Bt,
                                          u16* As, u16* Bs, f32x4 (&acc)[4][4]) {
  const int tid = threadIdx.x, wave = tid >> 6, lane = tid & 63;
  const int low = lane & 15, hi = lane >> 4;
  const int wm = wave >> 1, wn = wave & 1;
  const int m0 = blockIdx.y * BM, n0 = blockIdx.x * BN;
  const f32x4 fzero = {0.f, 0.f, 0.f, 0.f};
#pragma unroll
  for (int i = 0; i < 4; i++)
#pragma unroll
    for (int j = 0; j < 4; j++) acc[i][j] = fzero;

  const u16* ap = As + (wm * 64 + low) * BK + hi * 8;
  const u16* bp = Bs + (wn * 64 + low) * BK + hi * 8;

  const int e0 = wave * 128 + lane;
  const int e1 = e0 + 64;
  const u16* ga0 = A + (size_t)(m0 + (e0 >> 2)) * 1024 + (e0 & 3) * 8;
  const u16* ga1 = A + (size_t)(m0 + (e1 >> 2)) * 1024 + (e1 & 3) * 8;
  const u16* gb0 = Bt + (size_t)(n0 + (e0 >> 2)) * 1024 + (e0 & 3) * 8;
  const u16* gb1 = Bt + (size_t)(n0 + (e1 >> 2)) * 1024 + (e1 & 3) * 8;
  u16* la0 = As + (wave * 2 + 0) * 512;
  u16* la1 = As + (wave * 2 + 1) * 512;
  u16* lb0 = Bs + (wave * 2 + 0) * 512;
  u16* lb1 = Bs + (wave * 2 + 1) * 512;

  for (int kt = 0; kt < 1024; kt += BK) {
    __syncthreads();
    async16(ga0 + kt, la0);
    async16(ga1 + kt, la1);
    async16(gb0 + kt, lb0);
    async16(gb1 + kt, lb1);
    __syncthreads();
    bf16x8 af[4], bfv[4];
#pragma unroll
    for (int i = 0; i < 4; i++) af[i] = *(const bf16x8*)(ap + i * 16 * BK);
#pragma unroll
    for (int j = 0; j < 4; j++) bfv[j] = *(const bf16x8*)(bp + j * 16 * BK);
#pragma unroll
    for (int i = 0; i < 4; i++)
#pragma unroll
      for (int j = 0; j < 4; j++) acc[i][j] = mfma16(af[i], bfv[j], acc[i][j]);
  }
}

// QKV projection: out layouts  Q,K -> [BH][L][64],  V -> [BH][64][L]
// Q is pre-scaled by 0.125 * log2(e) (exp2-domain softmax downstream).
__global__ __launch_bounds__(256) void gemm_qkv_kernel(
    const u16* __restrict__ xb, const u16* __restrict__ wT,
    const float* __restrict__ bq, const float* __restrict__ bk,
    const float* __restrict__ bv,
    u16* __restrict__ qs, u16* __restrict__ ks, u16* __restrict__ vts) {
  __shared__ __align__(16) u16 As[BM * BK];
  __shared__ __align__(16) u16 Bs[BN * BK];
  const int z = blockIdx.z;
  const u16* Bt = wT + (size_t)z * (1u << 20);
  f32x4 acc[4][4];
  gemm_core(xb, Bt, As, Bs, acc);

  const float* bias = (z == 0) ? bq : (z == 1) ? bk : bv;
  u16* out = (z == 0) ? qs : (z == 1) ? ks : vts;
  const float scale = (z == 0) ? 0.180336880f : 1.0f;  // 0.125 * log2(e)
  const int tid = threadIdx.x, wave = tid >> 6, lane = tid & 63;
  const int low = lane & 15, hi = lane >> 4;
  const int wm = wave >> 1, wn = wave & 1;
  const int m0 = blockIdx.y * BM, n0 = blockIdx.x * BN;
#pragma unroll
  for (int i = 0; i < 4; i++)
#pragma unroll
    for (int j = 0; j < 4; j++) {
      int gn = n0 + wn * 64 + j * 16 + low;
      float bval = bias[gn];
      int h = gn >> 6, hd = gn & 63;
#pragma unroll
      for (int r = 0; r < 4; r++) {
        int gm = m0 + wm * 64 + i * 16 + hi * 4 + r;
        int b = gm >> 11, l = gm & 2047;
        float v = (acc[i][j][r] + bval) * scale;
        size_t addr;
        if (z == 2) addr = ((size_t)((b * 16 + h) * 64 + hd)) * 2048 + l;
        else        addr = ((size_t)((b * 16 + h) * 2048 + l)) * 64 + hd;
        out[addr] = f2bf(v);
      }
    }
}

// output projection: ctx[M][1024] @ WoT + bo -> fp32 out[M][1024]
__global__ __launch_bounds__(256) void gemm_out_kernel(
    const u16* __restrict__ ctx, const u16* __restrict__ woT,
    const float* __restrict__ bo, float* __restrict__ out) {
  __shared__ __align__(16) u16 As[BM * BK];
  __shared__ __align__(16) u16 Bs[BN * BK];
  f32x4 acc[4][4];
  gemm_core(ctx, woT, As, Bs, acc);
  const int tid = threadIdx.x, wave = tid >> 6, lane = tid & 63;
  const int low = lane & 15, hi = lane >> 4;
  const int wm = wave >> 1, wn = wave & 1;
  const int m0 = blockIdx.y * BM, n0 = blockIdx.x * BN;
#pragma unroll
  for (int i = 0; i < 4; i++)
#pragma unroll
    for (int j = 0; j < 4; j++) {
      int gn = n0 + wn * 64 + j * 16 + low;
      float bval = bo[gn];
#pragma unroll
      for (int r = 0; r < 4; r++) {
        int gm = m0 + wm * 64 + i * 16 + hi * 4 + r;
        out[(size_t)gm * 1024 + gn] = acc[i][j][r] + bval;
      }
    }
}

// ---------------- flash attention v4.1: 32x32 MFMA, in-register softmax ----
// 512 blocks; bid<256: qt=15-(bid>>5), else qt=(bid-256)>>5 (balanced pairs).
// 4 waves x 32 q rows. KV tiles 64, triple-buffered, counted vmcnt(4), one
// barrier/tile. Swapped QK^T via mfma_32x32x16 (lane owns q col = lane&31;
// k row = (r&3)+8*(r>>2)+4*hi2). PV uses the SAME slot mapping
// kappa(h,e) = (e&3)+8*(e>>2)+4h for both V (A-op, split b64 reads) and P
// (B-op, straight cvt_pk of adjacent accumulator regs) -> no cross-lane
// data movement for P at all. Reductions: __shfl_xor(,32) (known-good).
__global__ __launch_bounds__(256) void flash_kernel(
    const u16* __restrict__ Qs, const u16* __restrict__ Ks,
    const u16* __restrict__ Vts, u16* __restrict__ ctx) {
  __shared__ __align__(16) u16 Kls[3][64 * 64];
  __shared__ __align__(16) u16 Vls[3][64 * 64];

  const int bid = blockIdx.x;
  const int qt = (bid < 256) ? (15 - (bid >> 5)) : ((bid - 256) >> 5);
  const int bh = bid & 31;
  const int qb = qt * 128;
  const int nkv = 2 * qt + 2;

  const int tid = threadIdx.x, wave = tid >> 6, lane = tid & 63;
  const int q32 = lane & 31, hi2 = lane >> 5;
  const int x7 = q32 & 7;

  const u16* Qb = Qs + (size_t)bh * (2048 * 64);
  const u16* Kb = Ks + (size_t)bh * (2048 * 64);
  const u16* Vb = Vts + (size_t)bh * (64 * 2048);

  const int qrow = qb + wave * 32 + q32;
  // Q B-fragments: qf[ds] holds Q[qrow][d = ds*16 + hi2*8 + e]
  bf16x8 qf[4];
#pragma unroll
  for (int ds = 0; ds < 4; ds++)
    qf[ds] = *(const bf16x8*)(Qb + (size_t)qrow * 64 + ds * 16 + hi2 * 8);

  f32x16 o0, o1;
#pragma unroll
  for (int r = 0; r < 16; r++) { o0[r] = 0.f; o1[r] = 0.f; }
  float m_ = -1e30f, l_ = 0.f;

  const int srow0 = (lane >> 3);
  const int scc = lane & 7;

#define STAGE(buf, KT0)                                                        \
  {                                                                            \
    _Pragma("unroll") for (int i = 0; i < 2; i++) {                            \
      int row = (wave * 2 + i) * 8 + srow0;                                    \
      async16(Kb + (size_t)((KT0) + row) * 64 + ((scc ^ (row & 7)) * 8),       \
              &Kls[buf][(wave * 2 + i) * 512]);                                \
      async16(Vb + (size_t)row * 2048 + (KT0) + ((scc ^ (row & 7)) * 8),       \
              &Vls[buf][(wave * 2 + i) * 512]);                                \
    }                                                                          \
  }

  STAGE(0, 0)
  STAGE(1, 64)

  const int qmax = qb + wave * 32 + 31;

  int c0 = 0, c1 = 1, c2 = 2;
  for (int t = 0; t < nkv; t++) {
    const int kt0 = t * 64;
    if (t + 1 < nkv) { asm volatile("s_waitcnt vmcnt(4)" ::: "memory"); }
    else             { asm volatile("s_waitcnt vmcnt(0)" ::: "memory"); }
    __builtin_amdgcn_s_barrier();
    if (t + 2 < nkv) STAGE(c2, kt0 + 128)

    if (kt0 <= qmax) {
      const u16* Kc = &Kls[c0][0];
      const u16* Vc = &Vls[c0][0];

      // ---- QK^T: A = K rows (k), B = Q cols (q). s0: k 0..31, s1: k 32..63
      f32x16 s0, s1;
#pragma unroll
      for (int r = 0; r < 16; r++) { s0[r] = 0.f; s1[r] = 0.f; }
      __builtin_amdgcn_s_setprio(1);
#pragma unroll
      for (int ds = 0; ds < 4; ds++) {
        int cc = ds * 2 + hi2;
        bf16x8 kf0 = *(const bf16x8*)(Kc + q32 * 64 + ((cc ^ x7) * 8));
        bf16x8 kf1 = *(const bf16x8*)(Kc + (32 + q32) * 64 + ((cc ^ x7) * 8));
        s0 = mfma32(kf0, qf[ds], s0);
        s1 = mfma32(kf1, qf[ds], s1);
      }
      __builtin_amdgcn_s_setprio(0);

      // ---- V A-fragments early (slot mapping kappa(h,e)=(e&3)+8*(e>>2)+4h):
      // lane reads k = 16ks+4h..+3 (chunk 2ks, half h) and 16ks+8+4h..+3
      // (chunk 2ks+1, half h) for d-row q32 (vf0) and 32+q32 (vf1).
      bf16x8 vf0[4], vf1[4];
#pragma unroll
      for (int ks = 0; ks < 4; ks++) {
        int ca = (2 * ks) ^ x7, cb = (2 * ks + 1) ^ x7;
        union { uint2 u[2]; bf16x8 v; } a, b;
        a.u[0] = *(const uint2*)(Vc + q32 * 64 + ca * 8 + 4 * hi2);
        a.u[1] = *(const uint2*)(Vc + q32 * 64 + cb * 8 + 4 * hi2);
        b.u[0] = *(const uint2*)(Vc + (32 + q32) * 64 + ca * 8 + 4 * hi2);
        b.u[1] = *(const uint2*)(Vc + (32 + q32) * 64 + cb * 8 + 4 * hi2);
        vf0[ks] = a.v; vf1[ks] = b.v;
      }

      // ---- causal mask (k-local = (r&3) + 8*(r>>2) + 4*hi2) ----
      if (kt0 + 63 > qb + wave * 32) {
#pragma unroll
        for (int r = 0; r < 16; r++) {
          int kl = (r & 3) + 8 * (r >> 2) + 4 * hi2;
          if (kt0 + kl > qrow) s0[r] = -1e30f;
          if (kt0 + 32 + kl > qrow) s1[r] = -1e30f;
        }
      }

      // ---- row max ----
      float pm = -1e30f;
#pragma unroll
      for (int r = 0; r < 16; r++) pm = fmaxf(pm, fmaxf(s0[r], s1[r]));
      pm = fmaxf(pm, __shfl_xor(pm, 32));
      if (__any(pm > m_ + 8.f)) {
        float mn = fmaxf(m_, pm);
        float corr = __builtin_amdgcn_exp2f(m_ - mn);
        m_ = mn;
        l_ *= corr;
#pragma unroll
        for (int r = 0; r < 16; r++) { o0[r] *= corr; o1[r] *= corr; }
      }

      // ---- exp2 + row sum ----
      float rs = 0.f;
#pragma unroll
      for (int r = 0; r < 16; r++) {
        s0[r] = __builtin_amdgcn_exp2f(s0[r] - m_);
        s1[r] = __builtin_amdgcn_exp2f(s1[r] - m_);
        rs += s0[r] + s1[r];
      }
      rs += __shfl_xor(rs, 32);
      l_ += rs;

      // ---- P B-fragments: call ks covers k = 16ks..16ks+15; this lane's
      // 8 slots are exactly accumulator regs 8*(ks&1)..+7 of (ks<2?s0:s1).
      bf16x8 pb[4];
#pragma unroll
      for (int ks = 0; ks < 4; ks++) {
        union { uint32_t u[4]; bf16x8 v; } pu;
        if (ks < 2) {
          int rb = 8 * ks;
          pu.u[0] = cvtpk(s0[rb + 0], s0[rb + 1]);
          pu.u[1] = cvtpk(s0[rb + 2], s0[rb + 3]);
          pu.u[2] = cvtpk(s0[rb + 4], s0[rb + 5]);
          pu.u[3] = cvtpk(s0[rb + 6], s0[rb + 7]);
        } else {
          int rb = 8 * (ks - 2);
          pu.u[0] = cvtpk(s1[rb + 0], s1[rb + 1]);
          pu.u[1] = cvtpk(s1[rb + 2], s1[rb + 3]);
          pu.u[2] = cvtpk(s1[rb + 4], s1[rb + 5]);
          pu.u[3] = cvtpk(s1[rb + 6], s1[rb + 7]);
        }
        pb[ks] = pu.v;
      }

      // ---- PV: A = V^T rows (d), B = P cols (q), shared kappa ----
      __builtin_amdgcn_s_setprio(1);
#pragma unroll
      for (int ks = 0; ks < 4; ks++) {
        o0 = mfma32(vf0[ks], pb[ks], o0);
        o1 = mfma32(vf1[ks], pb[ks], o1);
      }
      __builtin_amdgcn_s_setprio(0);
    }

    int tmp = c0; c0 = c1; c1 = c2; c2 = tmp;
  }

  // ---- epilogue: O[q=q32][d = dtile*32 + (r&3)+8*(r>>2)+4*hi2] / l ----
  const int b = bh >> 4, h = bh & 15;
  float inv = 1.f / l_;
  size_t base = ((size_t)(b * 2048 + qrow)) * 1024 + h * 64;
#pragma unroll
  for (int m = 0; m < 4; m++) {
    uint2 w0, w1;
    w0.x = cvtpk(o0[4 * m + 0] * inv, o0[4 * m + 1] * inv);
    w0.y = cvtpk(o0[4 * m + 2] * inv, o0[4 * m + 3] * inv);
    *(uint2*)(ctx + base + 8 * m + 4 * hi2) = w0;
    w1.x = cvtpk(o1[4 * m + 0] * inv, o1[4 * m + 1] * inv);
    w1.y = cvtpk(o1[4 * m + 2] * inv, o1[4 * m + 3] * inv);
    *(uint2*)(ctx + base + 32 + 8 * m + 4 * hi2) = w1;
  }
}

// ---------------- launch ----------------

extern "C" void kernel_launch(void* const* d_in, const int* in_sizes, int n_in,
                              void* d_out, int out_size, void* d_ws, size_t ws_size,
                              hipStream_t stream) {
  const float* x  = (const float*)d_in[0];
  const float* Wq = (const float*)d_in[1];
  const float* bq = (const float*)d_in[2];
  const float* Wk = (const float*)d_in[3];
  const float* bk = (const float*)d_in[4];
  const float* Wv = (const float*)d_in[5];
  const float* bv = (const float*)d_in[6];
  const float* Wo = (const float*)d_in[7];
  const float* bo = (const float*)d_in[8];

  char* ws = (char*)d_ws;
  u16* xb  = (u16*)(ws);                    // [4096][1024] bf16, 8MB
  u16* wT  = (u16*)(ws + (8u << 20));       // 4 x [1024][1024] bf16, 8MB
  u16* qs  = (u16*)(ws + (16u << 20));      // [32][2048][64] bf16 (pre-scaled)
  u16* ks  = (u16*)(ws + (24u << 20));      // [32][2048][64] bf16
  u16* vts = (u16*)(ws + (32u << 20));      // [32][64][2048] bf16
  u16* ctx = (u16*)(ws + (40u << 20));      // [4096][1024] bf16

  x_cvt_kernel<<<4096, 256, 0, stream>>>(x, xb);
  wt_cvt_kernel<<<dim3(16, 16, 4), 256, 0, stream>>>(Wq, Wk, Wv, Wo, wT);
  gemm_qkv_kernel<<<dim3(8, 32, 3), 256, 0, stream>>>(xb, wT, bq, bk, bv, qs, ks, vts);
  flash_kernel<<<512, 256, 0, stream>>>(qs, ks, vts, ctx);
  gemm_out_kernel<<<dim3(8, 32), 256, 0, stream>>>(ctx, wT + 3 * (1u << 20), bo, (float*)d_out);
}